// Round 19
// baseline (148.487 us; speedup 1.0000x reference)
//
#include <hip/hip_runtime.h>
#include <hip/hip_bf16.h>
#include <stdint.h>

using f32x4  = __attribute__((ext_vector_type(4))) float;
using bf16x8 = __attribute__((ext_vector_type(8))) short;

constexpr int BATCH = 4;
constexpr int LQ_   = 256;
constexpr int LK_   = 50000;
constexpr int OUTD  = 256;
constexpr int EIN   = 128;
constexpr int TR    = 16;                      // k-rows per tile
constexpr int NT    = LK_ / TR;                // 3125 (exact)
constexpr int KCH   = 64;                      // k-chunks per batch (grid 256 = 1/CU)

__device__ __forceinline__ uint32_t f2bf(float f) {
  uint32_t u = __builtin_bit_cast(uint32_t, f);
  u = (u + 0x7fffu + ((u >> 16) & 1u)) >> 16;
  return u;
}

// LDS-only barrier: drains this wave's LDS ops, raw s_barrier, no vmcnt drain.
__device__ __forceinline__ void block_sync_lds() {
  asm volatile("s_waitcnt lgkmcnt(0)" ::: "memory");
  __builtin_amdgcn_sched_barrier(0);
  __builtin_amdgcn_s_barrier();
  __builtin_amdgcn_sched_barrier(0);
}

// ---- prep (fused): blocks 0-255 -> Gn quarter each (Q recomputed in-LDS);
//      blocks 256-287 -> cast Wv->bf16; block 288 -> zero num/den + counters.
__global__ __launch_bounds__(256) void prep_fused(
    const float* __restrict__ query, const float* __restrict__ Wq,
    const float* __restrict__ bq,    const float* __restrict__ Wk,
    const float* __restrict__ Wv,    ushort* __restrict__ Gn,
    ushort* __restrict__ Wvbf,       float* __restrict__ numden,
    int* __restrict__ cnt)
{
  const int blk = blockIdx.x, tid = threadIdx.x;
  if (blk >= 256) {
    if (blk < 288) {                      // cast Wv -> bf16 (32 blocks x 2048)
      int base = (blk - 256) * 2048 + tid * 8;
      float4 a = *(const float4*)(Wv + base);
      float4 c = *(const float4*)(Wv + base + 4);
      uint4 pk;
      pk.x = f2bf(a.x) | (f2bf(a.y) << 16);
      pk.y = f2bf(a.z) | (f2bf(a.w) << 16);
      pk.z = f2bf(c.x) | (f2bf(c.y) << 16);
      pk.w = f2bf(c.z) | (f2bf(c.w) << 16);
      *(uint4*)(Wvbf + base) = pk;
    } else {                              // zero accumulators + arrival counters
      for (int i = tid; i < 2 * BATCH * OUTD; i += 256) numden[i] = 0.f;
      if (tid < BATCH) cnt[tid] = 0;
    }
    return;
  }
  // ---- Gn quarter: b = blk>>6, q0 = ((blk>>2)&15)*16, colg = blk&3 --------
  __shared__ float qin[16 * EIN];    // 8 KB
  __shared__ float Qr [16 * OUTD];   // 16 KB
  const int b = blk >> 6, q0 = ((blk >> 2) & 15) * 16, colg = blk & 3;
  {
    int idx = tid * 8;
    int row = idx >> 7, c = idx & 127;
    const float* p = query + ((size_t)b * LQ_ + q0 + row) * EIN + c;
    float4 a = *(const float4*)p;
    float4 d = *(const float4*)(p + 4);
    float* q = &qin[row * EIN + c];
    q[0]=a.x; q[1]=a.y; q[2]=a.z; q[3]=a.w; q[4]=d.x; q[5]=d.y; q[6]=d.z; q[7]=d.w;
  }
  __syncthreads();

  // phase 1 (redundant x4 across colg): Q[i][tid] = bq[tid] + qin[i]·Wq[tid]
  float acc[16];
  {
    float bias = bq[tid];
#pragma unroll
    for (int i = 0; i < 16; ++i) acc[i] = bias;
  }
  for (int d4 = 0; d4 < EIN / 4; ++d4) {
    f32x4 w4 = *(const f32x4*)(Wq + tid * EIN + d4 * 4);
#pragma unroll
    for (int i = 0; i < 16; ++i) {
      f32x4 q4 = *(const f32x4*)(qin + i * EIN + d4 * 4);
      acc[i] += q4[0]*w4[0] + q4[1]*w4[1] + q4[2]*w4[2] + q4[3]*w4[3];
    }
  }
#pragma unroll
  for (int i = 0; i < 16; ++i) Qr[i * OUTD + tid] = acc[i];
  __syncthreads();

  // phase 2: this block's 64-column quarter of Gn = (log2e/16) * Q @ Wk
  const int col = colg * 64 + (tid & 63), rg = tid >> 6;
  float acc2[4] = {0.f, 0.f, 0.f, 0.f};
  for (int d = 0; d < OUTD; ++d) {
    float wv = Wk[d * OUTD + col];
#pragma unroll
    for (int i = 0; i < 4; ++i) acc2[i] += Qr[(rg * 4 + i) * OUTD + d] * wv;
  }
  const float nrm = 1.4426950408889634f * 0.0625f;  // log2(e)/sqrt(256)
#pragma unroll
  for (int i = 0; i < 4; ++i)
    Gn[((size_t)b * LQ_ + q0 + rg * 4 + i) * OUTD + col] = (ushort)f2bf(acc2[i] * nrm);
}

// ---- main: R18 attn verbatim + fused finalize tail -------------------------
// 256 blocks (1/CU), 1024 thr = 16 waves; wave w owns q-rows [w*16,w*16+16).
// A-frags 64 VGPR pinned; 2x8KB swizzled bf16 LDS dbuf; reg-staged coalesced
// loads; single lgkm-only barrier/iter; e = exp2f (log2e folded into Gn).
// Tail: last-arriving block per batch (device-scope counter) computes
// out = num/den + bv, reading num/den via atomicAdd(p,0) (XCD-coherent).
__global__ __launch_bounds__(1024, 4) void attn_main(
    const float*  __restrict__ input, const ushort* __restrict__ Gn,
    const ushort* __restrict__ Wvbf,  float* __restrict__ num,
    float* __restrict__ den,          const float* __restrict__ bv,
    int* __restrict__ cnt,            float* __restrict__ out)
{
  __shared__ ushort in_lds[2 * 4096]; // 2 x 8 KB
  __shared__ int last_flag;
  const int idx = blockIdx.x;
  const int b = idx >> 6, kch = idx & (KCH - 1);
  const int t0 = (kch * NT) >> 6, t1 = ((kch + 1) * NT) >> 6;
  const int tid = threadIdx.x, w = tid >> 6, l = tid & 63;
  const int lg = l >> 4, lr = l & 15;
  const float* src = input + (size_t)b * LK_ * 256;

  const int arow = w * 16 + lr;
  const ushort* gp = Gn   + ((size_t)b * LQ_ + arow) * 256 + lg * 8;
  const ushort* vp = Wvbf + (size_t)arow * 256 + lg * 8;
  bf16x8 ga[8], wa[8];
#pragma unroll
  for (int k = 0; k < 8; ++k) {
    ga[k] = *(const bf16x8*)(gp + k * 32);
    wa[k] = *(const bf16x8*)(vp + k * 32);
    asm volatile("" : "+v"(ga[k]), "+v"(wa[k]));  // forbid remat/sink
  }

  float numr[4], denr[4];
#pragma unroll
  for (int r = 0; r < 4; ++r) { numr[r] = 0.f; denr[r] = 0.f; }

  const int sg = tid >> 1, sh = tid & 1;
  const int srow = sg >> 5, sfbg = sg & 31;
  float4 s0;
  auto loadreg = [&](int t) {
    const float* p = src + (size_t)(t * TR + srow) * 256 + sfbg * 8 + sh * 4;
    s0 = *(const float4*)p;
  };
  auto writebuf = [&](int buf) {
    char* base = (char*)in_lds + buf * 8192;
    uint2 pk;
    pk.x = f2bf(s0.x) | (f2bf(s0.y) << 16);
    pk.y = f2bf(s0.z) | (f2bf(s0.w) << 16);
    *(uint2*)(base + sfbg * 256 + ((srow ^ (sfbg & 15)) << 4) + sh * 8) = pk;
  };

  loadreg(t0);
  writebuf(t0 & 1);
  loadreg(t0 + 1);
  block_sync_lds();

  for (int t = t0; t < t1; ++t) {
    const char* bbuf = (const char*)in_lds + (t & 1) * 8192;
    f32x4 aS = {0,0,0,0};
    f32x4 aV = {0,0,0,0};
#pragma unroll
    for (int ks = 0; ks < 8; ++ks) {
      const int fb = ks * 4 + lg;
      bf16x8 bb = *(const bf16x8*)(bbuf + fb * 256 + ((lr ^ (fb & 15)) << 4));
      aS = __builtin_amdgcn_mfma_f32_16x16x32_bf16(ga[ks], bb, aS, 0, 0, 0);
      aV = __builtin_amdgcn_mfma_f32_16x16x32_bf16(wa[ks], bb, aV, 0, 0, 0);
    }
#pragma unroll
    for (int r = 0; r < 4; ++r) {
      float e = exp2f(aS[r]);       // bare v_exp_f32 (log2e pre-folded)
      denr[r] += e;
      numr[r] += e * aV[r];
    }
    if (t + 1 < t1) {
      writebuf((t + 1) & 1);
      if (t + 2 < t1) loadreg(t + 2);
    }
    block_sync_lds();
  }

#pragma unroll
  for (int r = 0; r < 4; ++r) {
    float d_ = denr[r], n_ = numr[r];
#pragma unroll
    for (int m = 1; m < 16; m <<= 1) {
      d_ += __shfl_xor(d_, m, 64);
      n_ += __shfl_xor(n_, m, 64);
    }
    if (lr == 0) {
      int q = w * 16 + lg * 4 + r;
      atomicAdd(&den[b * OUTD + q], d_);
      atomicAdd(&num[b * OUTD + q], n_);
    }
  }

  // ---- fused finalize: last arrival of batch b writes out[b] ----
  __threadfence();                   // make this block's adds visible
  if (tid == 0)
    last_flag = (atomicAdd(&cnt[b], 1) == KCH - 1) ? 1 : 0;
  __syncthreads();
  if (last_flag && tid < OUTD) {
    float n_ = atomicAdd(&num[b * OUTD + tid], 0.f);   // coherent read
    float d_ = atomicAdd(&den[b * OUTD + tid], 0.f);
    out[b * OUTD + tid] = n_ / d_ + bv[tid];
  }
}

extern "C" void kernel_launch(void* const* d_in, const int* in_sizes, int n_in,
                              void* d_out, int out_size, void* d_ws, size_t ws_size,
                              hipStream_t stream)
{
  const float* query = (const float*)d_in[0];
  const float* input = (const float*)d_in[1];
  const float* Wq    = (const float*)d_in[2];
  const float* bq    = (const float*)d_in[3];
  const float* Wk    = (const float*)d_in[4];
  // d_in[5] = bk : softmax-invariant, unused
  const float* Wv    = (const float*)d_in[6];
  const float* bv    = (const float*)d_in[7];
  float* out = (float*)d_out;

  char* ws = (char*)d_ws;
  ushort* Gn     = (ushort*)ws;                       // 512 KB
  ushort* Wvbf   = (ushort*)(ws + 524288);            // 128 KB
  float*  numden = (float*)(ws + 524288 + 131072);    // 8 KB
  float*  num    = numden;
  float*  den    = numden + BATCH * OUTD;
  int*    cnt    = (int*)(ws + 524288 + 131072 + 8192);  // 16 B

  prep_fused<<<289, 256, 0, stream>>>(query, Wq, bq, Wk, Wv, Gn, Wvbf, numden, cnt);
  attn_main<<<BATCH * KCH, 1024, 0, stream>>>(input, Gn, Wvbf, num, den, bv, cnt, out);
}

// Round 20
// 98.751 us; speedup vs baseline: 1.5037x; 1.5037x over previous
//
#include <hip/hip_runtime.h>
#include <hip/hip_bf16.h>
#include <stdint.h>

using f32x4  = __attribute__((ext_vector_type(4))) float;
using bf16x8 = __attribute__((ext_vector_type(8))) short;

constexpr int BATCH = 4;
constexpr int LQ_   = 256;
constexpr int LK_   = 50000;
constexpr int OUTD  = 256;
constexpr int EIN   = 128;
constexpr int TR    = 16;                      // k-rows per tile
constexpr int NT    = LK_ / TR;                // 3125 (exact)
constexpr int KCH   = 64;                      // k-chunks per batch (grid 256 = 1/CU)

__device__ __forceinline__ uint32_t f2bf(float f) {
  uint32_t u = __builtin_bit_cast(uint32_t, f);
  u = (u + 0x7fffu + ((u >> 16) & 1u)) >> 16;
  return u;
}

// LDS-only barrier: drains this wave's LDS ops, raw s_barrier, no vmcnt drain.
__device__ __forceinline__ void block_sync_lds() {
  asm volatile("s_waitcnt lgkmcnt(0)" ::: "memory");
  __builtin_amdgcn_sched_barrier(0);
  __builtin_amdgcn_s_barrier();
  __builtin_amdgcn_sched_barrier(0);
}

// ---- prep1: blocks 0-63 -> Q = query@Wq^T + bq (f32, to ws);
//             blocks 64-95 -> cast Wv->bf16; block 96 -> zero num/den -------
__global__ __launch_bounds__(256) void prep1(
    const float* __restrict__ query, const float* __restrict__ Wq,
    const float* __restrict__ bq,    const float* __restrict__ Wv,
    float* __restrict__ Qws,         ushort* __restrict__ Wvbf,
    float* __restrict__ numden)
{
  const int blk = blockIdx.x, tid = threadIdx.x;
  if (blk >= 64) {
    if (blk < 96) {                       // cast Wv -> bf16 (32 blocks x 2048)
      int base = (blk - 64) * 2048 + tid * 8;
      float4 a = *(const float4*)(Wv + base);
      float4 c = *(const float4*)(Wv + base + 4);
      uint4 pk;
      pk.x = f2bf(a.x) | (f2bf(a.y) << 16);
      pk.y = f2bf(a.z) | (f2bf(a.w) << 16);
      pk.z = f2bf(c.x) | (f2bf(c.y) << 16);
      pk.w = f2bf(c.z) | (f2bf(c.w) << 16);
      *(uint4*)(Wvbf + base) = pk;
    } else {
      for (int i = tid; i < 2 * BATCH * OUTD; i += 256) numden[i] = 0.f;
    }
    return;
  }
  __shared__ float qin[16 * EIN];    // 8 KB
  const int b = blk >> 4, q0 = (blk & 15) * 16;
  {
    int idx = tid * 8;
    int row = idx >> 7, c = idx & 127;
    const float* p = query + ((size_t)b * LQ_ + q0 + row) * EIN + c;
    float4 a = *(const float4*)p;
    float4 d = *(const float4*)(p + 4);
    float* q = &qin[row * EIN + c];
    q[0]=a.x; q[1]=a.y; q[2]=a.z; q[3]=a.w; q[4]=d.x; q[5]=d.y; q[6]=d.z; q[7]=d.w;
  }
  __syncthreads();

  float acc[16];
  {
    float bias = bq[tid];
#pragma unroll
    for (int i = 0; i < 16; ++i) acc[i] = bias;
  }
  for (int d4 = 0; d4 < EIN / 4; ++d4) {
    f32x4 w4 = *(const f32x4*)(Wq + tid * EIN + d4 * 4);
#pragma unroll
    for (int i = 0; i < 16; ++i) {
      f32x4 q4 = *(const f32x4*)(qin + i * EIN + d4 * 4);
      acc[i] += q4[0]*w4[0] + q4[1]*w4[1] + q4[2]*w4[2] + q4[3]*w4[3];
    }
  }
#pragma unroll
  for (int i = 0; i < 16; ++i)
    Qws[((size_t)b * LQ_ + q0 + i) * OUTD + tid] = acc[i];
}

// ---- prep2: Gn = (log2e/16) * Q @ Wk  -> bf16. 256 blocks, 4x parallel ----
// block = (b, q16, colg): b = blk>>6, q0 = ((blk>>2)&15)*16, colg = blk&3.
__global__ __launch_bounds__(256) void prep2(
    const float* __restrict__ Qws, const float* __restrict__ Wk,
    ushort* __restrict__ Gn)
{
  __shared__ float Qr[16 * OUTD];    // 16 KB
  const int blk = blockIdx.x, tid = threadIdx.x;
  const int b = blk >> 6, q0 = ((blk >> 2) & 15) * 16, colg = blk & 3;
  {  // stage Q rows [q0, q0+16) fully (all 256 cols)
    int idx = tid * 16;
    int row = idx >> 8, c = idx & 255;
    const float* p = Qws + ((size_t)b * LQ_ + q0 + row) * OUTD + c;
    float4* q = (float4*)&Qr[row * OUTD + c];
    q[0] = *(const float4*)p;
    q[1] = *(const float4*)(p + 4);
    q[2] = *(const float4*)(p + 8);
    q[3] = *(const float4*)(p + 12);
  }
  __syncthreads();

  // thread -> (col = colg*64 + tid&63, rows rg*4 .. rg*4+4) of 16
  const int col = colg * 64 + (tid & 63), rg = tid >> 6;
  float acc[4] = {0.f, 0.f, 0.f, 0.f};
  for (int d = 0; d < OUTD; ++d) {
    float wv = Wk[d * OUTD + col];
#pragma unroll
    for (int i = 0; i < 4; ++i) acc[i] += Qr[(rg * 4 + i) * OUTD + d] * wv;
  }
  const float nrm = 1.4426950408889634f * 0.0625f;  // log2(e)/sqrt(256)
#pragma unroll
  for (int i = 0; i < 4; ++i)
    Gn[((size_t)b * LQ_ + q0 + rg * 4 + i) * OUTD + col] = (ushort)f2bf(acc[i] * nrm);
}

// ---- main: R11 structure + exp2 (log2e folded into Gn) ---------------------
// 256 blocks (1/CU), 1024 thr = 16 waves; wave w owns q-rows [w*16,w*16+16).
// A-frags 64 VGPR pinned; 2x8KB swizzled bf16 LDS dbuf; reg-staged coalesced
// loads; single lgkm-only barrier/iter; prefetch one tile ahead. Scores come
// out of MFMA pre-scaled by log2e -> e = exp2f(S') = bare v_exp_f32 (softmax
// invariant under exponent-base change).
__global__ __launch_bounds__(1024, 4) void attn_main(
    const float*  __restrict__ input, const ushort* __restrict__ Gn,
    const ushort* __restrict__ Wvbf,  float* __restrict__ num,
    float* __restrict__ den)
{
  __shared__ ushort in_lds[2 * 4096]; // 2 x 8 KB
  const int idx = blockIdx.x;
  const int b = idx >> 6, kch = idx & (KCH - 1);
  const int t0 = (kch * NT) >> 6, t1 = ((kch + 1) * NT) >> 6;
  const int tid = threadIdx.x, w = tid >> 6, l = tid & 63;
  const int lg = l >> 4, lr = l & 15;
  const float* src = input + (size_t)b * LK_ * 256;

  const int arow = w * 16 + lr;
  const ushort* gp = Gn   + ((size_t)b * LQ_ + arow) * 256 + lg * 8;
  const ushort* vp = Wvbf + (size_t)arow * 256 + lg * 8;
  bf16x8 ga[8], wa[8];
#pragma unroll
  for (int k = 0; k < 8; ++k) {
    ga[k] = *(const bf16x8*)(gp + k * 32);
    wa[k] = *(const bf16x8*)(vp + k * 32);
    asm volatile("" : "+v"(ga[k]), "+v"(wa[k]));  // forbid remat/sink
  }

  float numr[4], denr[4];
#pragma unroll
  for (int r = 0; r < 4; ++r) { numr[r] = 0.f; denr[r] = 0.f; }

  const int sg = tid >> 1, sh = tid & 1;
  const int srow = sg >> 5, sfbg = sg & 31;
  float4 s0;
  auto loadreg = [&](int t) {
    const float* p = src + (size_t)(t * TR + srow) * 256 + sfbg * 8 + sh * 4;
    s0 = *(const float4*)p;
  };
  auto writebuf = [&](int buf) {
    char* base = (char*)in_lds + buf * 8192;
    uint2 pk;
    pk.x = f2bf(s0.x) | (f2bf(s0.y) << 16);
    pk.y = f2bf(s0.z) | (f2bf(s0.w) << 16);
    *(uint2*)(base + sfbg * 256 + ((srow ^ (sfbg & 15)) << 4) + sh * 8) = pk;
  };

  loadreg(t0);
  writebuf(t0 & 1);
  loadreg(t0 + 1);
  block_sync_lds();

  for (int t = t0; t < t1; ++t) {
    const char* bbuf = (const char*)in_lds + (t & 1) * 8192;
    f32x4 aS = {0,0,0,0};
    f32x4 aV = {0,0,0,0};
#pragma unroll
    for (int ks = 0; ks < 8; ++ks) {
      const int fb = ks * 4 + lg;
      bf16x8 bb = *(const bf16x8*)(bbuf + fb * 256 + ((lr ^ (fb & 15)) << 4));
      aS = __builtin_amdgcn_mfma_f32_16x16x32_bf16(ga[ks], bb, aS, 0, 0, 0);
      aV = __builtin_amdgcn_mfma_f32_16x16x32_bf16(wa[ks], bb, aV, 0, 0, 0);
    }
#pragma unroll
    for (int r = 0; r < 4; ++r) {
      float e = exp2f(aS[r]);       // bare v_exp_f32 (log2e pre-folded)
      denr[r] += e;
      numr[r] += e * aV[r];
    }
    if (t + 1 < t1) {
      writebuf((t + 1) & 1);
      if (t + 2 < t1) loadreg(t + 2);
    }
    block_sync_lds();
  }

#pragma unroll
  for (int r = 0; r < 4; ++r) {
    float d_ = denr[r], n_ = numr[r];
#pragma unroll
    for (int m = 1; m < 16; m <<= 1) {
      d_ += __shfl_xor(d_, m, 64);
      n_ += __shfl_xor(n_, m, 64);
    }
    if (lr == 0) {
      int q = w * 16 + lg * 4 + r;
      atomicAdd(&den[b * OUTD + q], d_);
      atomicAdd(&num[b * OUTD + q], n_);
    }
  }
}

// ---- finalize: out = num/den + bv ------------------------------------------
__global__ __launch_bounds__(256) void finalize(const float* __restrict__ num,
                                                const float* __restrict__ den,
                                                const float* __restrict__ bv,
                                                float* __restrict__ out) {
  int i = blockIdx.x * 256 + threadIdx.x;
  out[i] = num[i] / den[i] + bv[i & 255];
}

extern "C" void kernel_launch(void* const* d_in, const int* in_sizes, int n_in,
                              void* d_out, int out_size, void* d_ws, size_t ws_size,
                              hipStream_t stream)
{
  const float* query = (const float*)d_in[0];
  const float* input = (const float*)d_in[1];
  const float* Wq    = (const float*)d_in[2];
  const float* bq    = (const float*)d_in[3];
  const float* Wk    = (const float*)d_in[4];
  // d_in[5] = bk : softmax-invariant, unused
  const float* Wv    = (const float*)d_in[6];
  const float* bv    = (const float*)d_in[7];
  float* out = (float*)d_out;

  char* ws = (char*)d_ws;
  ushort* Gn     = (ushort*)ws;                       // 512 KB
  ushort* Wvbf   = (ushort*)(ws + 524288);            // 128 KB
  float*  numden = (float*)(ws + 524288 + 131072);    // 8 KB
  float*  num    = numden;
  float*  den    = numden + BATCH * OUTD;
  float*  Qws    = (float*)(ws + 524288 + 131072 + 8192);  // 1 MB (f32 Q)

  prep1<<<97, 256, 0, stream>>>(query, Wq, bq, Wv, Qws, Wvbf, numden);
  prep2<<<256, 256, 0, stream>>>(Qws, Wk, Gn);
  attn_main<<<BATCH * KCH, 1024, 0, stream>>>(input, Gn, Wvbf, num, den);
  finalize<<<BATCH, 256, 0, stream>>>(num, den, bv, out);
}

// Round 21
// 95.410 us; speedup vs baseline: 1.5563x; 1.0350x over previous
//
#include <hip/hip_runtime.h>
#include <hip/hip_bf16.h>
#include <stdint.h>

using f32x4  = __attribute__((ext_vector_type(4))) float;
using bf16x8 = __attribute__((ext_vector_type(8))) short;

constexpr int BATCH = 4;
constexpr int LQ_   = 256;
constexpr int LK_   = 50000;
constexpr int OUTD  = 256;
constexpr int EIN   = 128;
constexpr int TR    = 16;                      // k-rows per tile
constexpr int NT    = LK_ / TR;                // 3125 (exact)
constexpr int KCH   = 64;                      // k-chunks per batch (grid 256 = 1/CU)

__device__ __forceinline__ uint32_t f2bf(float f) {
  uint32_t u = __builtin_bit_cast(uint32_t, f);
  u = (u + 0x7fffu + ((u >> 16) & 1u)) >> 16;
  return u;
}

// LDS-only barrier: drains this wave's LDS ops, raw s_barrier, no vmcnt drain.
__device__ __forceinline__ void block_sync_lds() {
  asm volatile("s_waitcnt lgkmcnt(0)" ::: "memory");
  __builtin_amdgcn_sched_barrier(0);
  __builtin_amdgcn_s_barrier();
  __builtin_amdgcn_sched_barrier(0);
}

// ---- prep (fused, proven in R19): blocks 0-255 -> Gn quarter each (Q
// recomputed in-LDS, x4 redundant -- cheaper than a launch gap + Qws HBM
// round-trip); blocks 256-287 -> cast Wv->bf16; block 288 -> zero num/den.
__global__ __launch_bounds__(256) void prep_fused(
    const float* __restrict__ query, const float* __restrict__ Wq,
    const float* __restrict__ bq,    const float* __restrict__ Wk,
    const float* __restrict__ Wv,    ushort* __restrict__ Gn,
    ushort* __restrict__ Wvbf,       float* __restrict__ numden)
{
  const int blk = blockIdx.x, tid = threadIdx.x;
  if (blk >= 256) {
    if (blk < 288) {                      // cast Wv -> bf16 (32 blocks x 2048)
      int base = (blk - 256) * 2048 + tid * 8;
      float4 a = *(const float4*)(Wv + base);
      float4 c = *(const float4*)(Wv + base + 4);
      uint4 pk;
      pk.x = f2bf(a.x) | (f2bf(a.y) << 16);
      pk.y = f2bf(a.z) | (f2bf(a.w) << 16);
      pk.z = f2bf(c.x) | (f2bf(c.y) << 16);
      pk.w = f2bf(c.z) | (f2bf(c.w) << 16);
      *(uint4*)(Wvbf + base) = pk;
    } else {                              // zero the atomic accumulators
      for (int i = tid; i < 2 * BATCH * OUTD; i += 256) numden[i] = 0.f;
    }
    return;
  }
  // ---- Gn quarter: b = blk>>6, q0 = ((blk>>2)&15)*16, colg = blk&3 --------
  __shared__ float qin[16 * EIN];    // 8 KB
  __shared__ float Qr [16 * OUTD];   // 16 KB
  const int b = blk >> 6, q0 = ((blk >> 2) & 15) * 16, colg = blk & 3;
  {
    int idx = tid * 8;
    int row = idx >> 7, c = idx & 127;
    const float* p = query + ((size_t)b * LQ_ + q0 + row) * EIN + c;
    float4 a = *(const float4*)p;
    float4 d = *(const float4*)(p + 4);
    float* q = &qin[row * EIN + c];
    q[0]=a.x; q[1]=a.y; q[2]=a.z; q[3]=a.w; q[4]=d.x; q[5]=d.y; q[6]=d.z; q[7]=d.w;
  }
  __syncthreads();

  // phase 1 (redundant x4 across colg): Q[i][tid] = bq[tid] + qin[i]·Wq[tid]
  float acc[16];
  {
    float bias = bq[tid];
#pragma unroll
    for (int i = 0; i < 16; ++i) acc[i] = bias;
  }
  for (int d4 = 0; d4 < EIN / 4; ++d4) {
    f32x4 w4 = *(const f32x4*)(Wq + tid * EIN + d4 * 4);
#pragma unroll
    for (int i = 0; i < 16; ++i) {
      f32x4 q4 = *(const f32x4*)(qin + i * EIN + d4 * 4);
      acc[i] += q4[0]*w4[0] + q4[1]*w4[1] + q4[2]*w4[2] + q4[3]*w4[3];
    }
  }
#pragma unroll
  for (int i = 0; i < 16; ++i) Qr[i * OUTD + tid] = acc[i];
  __syncthreads();

  // phase 2: this block's 64-column quarter of Gn = (log2e/16) * Q @ Wk
  const int col = colg * 64 + (tid & 63), rg = tid >> 6;
  float acc2[4] = {0.f, 0.f, 0.f, 0.f};
  for (int d = 0; d < OUTD; ++d) {
    float wv = Wk[d * OUTD + col];
#pragma unroll
    for (int i = 0; i < 4; ++i) acc2[i] += Qr[(rg * 4 + i) * OUTD + d] * wv;
  }
  const float nrm = 1.4426950408889634f * 0.0625f;  // log2(e)/sqrt(256)
#pragma unroll
  for (int i = 0; i < 4; ++i)
    Gn[((size_t)b * LQ_ + q0 + rg * 4 + i) * OUTD + col] = (ushort)f2bf(acc2[i] * nrm);
}

// ---- main: R18/R20 VERBATIM (98.5/98.8 us, VGPR~112, reproduced twice) -----
// 256 blocks (1/CU), 1024 thr = 16 waves; wave w owns q-rows [w*16,w*16+16).
// A-frags 64 VGPR pinned; 2x8KB swizzled bf16 LDS dbuf; reg-staged coalesced
// loads; single lgkm-only barrier/iter; e = exp2f (log2e folded into Gn).
// Structural plateau documented: per-wave MFMA forces 16x B-tile re-read from
// LDS (64 cyc/k-row floor at this redundancy); escape requires >128 VGPR
// A-frag payloads, which the 16-waves/CU occupancy step forbids (allocator
// demotes; proven R5/R6/R8/R15). Remaining gap is below source level.
__global__ __launch_bounds__(1024, 4) void attn_main(
    const float*  __restrict__ input, const ushort* __restrict__ Gn,
    const ushort* __restrict__ Wvbf,  float* __restrict__ num,
    float* __restrict__ den)
{
  __shared__ ushort in_lds[2 * 4096]; // 2 x 8 KB
  const int idx = blockIdx.x;
  const int b = idx >> 6, kch = idx & (KCH - 1);
  const int t0 = (kch * NT) >> 6, t1 = ((kch + 1) * NT) >> 6;
  const int tid = threadIdx.x, w = tid >> 6, l = tid & 63;
  const int lg = l >> 4, lr = l & 15;
  const float* src = input + (size_t)b * LK_ * 256;

  const int arow = w * 16 + lr;
  const ushort* gp = Gn   + ((size_t)b * LQ_ + arow) * 256 + lg * 8;
  const ushort* vp = Wvbf + (size_t)arow * 256 + lg * 8;
  bf16x8 ga[8], wa[8];
#pragma unroll
  for (int k = 0; k < 8; ++k) {
    ga[k] = *(const bf16x8*)(gp + k * 32);
    wa[k] = *(const bf16x8*)(vp + k * 32);
    asm volatile("" : "+v"(ga[k]), "+v"(wa[k]));  // forbid remat/sink
  }

  float numr[4], denr[4];
#pragma unroll
  for (int r = 0; r < 4; ++r) { numr[r] = 0.f; denr[r] = 0.f; }

  const int sg = tid >> 1, sh = tid & 1;
  const int srow = sg >> 5, sfbg = sg & 31;
  float4 s0;
  auto loadreg = [&](int t) {
    const float* p = src + (size_t)(t * TR + srow) * 256 + sfbg * 8 + sh * 4;
    s0 = *(const float4*)p;
  };
  auto writebuf = [&](int buf) {
    char* base = (char*)in_lds + buf * 8192;
    uint2 pk;
    pk.x = f2bf(s0.x) | (f2bf(s0.y) << 16);
    pk.y = f2bf(s0.z) | (f2bf(s0.w) << 16);
    *(uint2*)(base + sfbg * 256 + ((srow ^ (sfbg & 15)) << 4) + sh * 8) = pk;
  };

  loadreg(t0);
  writebuf(t0 & 1);
  loadreg(t0 + 1);
  block_sync_lds();

  for (int t = t0; t < t1; ++t) {
    const char* bbuf = (const char*)in_lds + (t & 1) * 8192;
    f32x4 aS = {0,0,0,0};
    f32x4 aV = {0,0,0,0};
#pragma unroll
    for (int ks = 0; ks < 8; ++ks) {
      const int fb = ks * 4 + lg;
      bf16x8 bb = *(const bf16x8*)(bbuf + fb * 256 + ((lr ^ (fb & 15)) << 4));
      aS = __builtin_amdgcn_mfma_f32_16x16x32_bf16(ga[ks], bb, aS, 0, 0, 0);
      aV = __builtin_amdgcn_mfma_f32_16x16x32_bf16(wa[ks], bb, aV, 0, 0, 0);
    }
#pragma unroll
    for (int r = 0; r < 4; ++r) {
      float e = exp2f(aS[r]);       // bare v_exp_f32 (log2e pre-folded)
      denr[r] += e;
      numr[r] += e * aV[r];
    }
    if (t + 1 < t1) {
      writebuf((t + 1) & 1);
      if (t + 2 < t1) loadreg(t + 2);
    }
    block_sync_lds();
  }

#pragma unroll
  for (int r = 0; r < 4; ++r) {
    float d_ = denr[r], n_ = numr[r];
#pragma unroll
    for (int m = 1; m < 16; m <<= 1) {
      d_ += __shfl_xor(d_, m, 64);
      n_ += __shfl_xor(n_, m, 64);
    }
    if (lr == 0) {
      int q = w * 16 + lg * 4 + r;
      atomicAdd(&den[b * OUTD + q], d_);
      atomicAdd(&num[b * OUTD + q], n_);
    }
  }
}

// ---- finalize: out = num/den + bv ------------------------------------------
__global__ __launch_bounds__(256) void finalize(const float* __restrict__ num,
                                                const float* __restrict__ den,
                                                const float* __restrict__ bv,
                                                float* __restrict__ out) {
  int i = blockIdx.x * 256 + threadIdx.x;
  out[i] = num[i] / den[i] + bv[i & 255];
}

extern "C" void kernel_launch(void* const* d_in, const int* in_sizes, int n_in,
                              void* d_out, int out_size, void* d_ws, size_t ws_size,
                              hipStream_t stream)
{
  const float* query = (const float*)d_in[0];
  const float* input = (const float*)d_in[1];
  const float* Wq    = (const float*)d_in[2];
  const float* bq    = (const float*)d_in[3];
  const float* Wk    = (const float*)d_in[4];
  // d_in[5] = bk : softmax-invariant, unused
  const float* Wv    = (const float*)d_in[6];
  const float* bv    = (const float*)d_in[7];
  float* out = (float*)d_out;

  char* ws = (char*)d_ws;
  ushort* Gn     = (ushort*)ws;                       // 512 KB
  ushort* Wvbf   = (ushort*)(ws + 524288);            // 128 KB
  float*  numden = (float*)(ws + 524288 + 131072);    // 8 KB
  float*  num    = numden;
  float*  den    = numden + BATCH * OUTD;

  prep_fused<<<289, 256, 0, stream>>>(query, Wq, bq, Wk, Wv, Gn, Wvbf, numden);
  attn_main<<<BATCH * KCH, 1024, 0, stream>>>(input, Gn, Wvbf, num, den);
  finalize<<<BATCH, 256, 0, stream>>>(num, den, bv, out);
}